// Round 22
// baseline (397.938 us; speedup 1.0000x reference)
//
#include <hip/hip_runtime.h>

typedef __attribute__((ext_vector_type(8))) short s16x8;
typedef __attribute__((ext_vector_type(4))) float f32x4;
typedef unsigned short u16;

#define DEV __device__ __forceinline__

DEV u16 f2b(float f) {
  unsigned u = __builtin_bit_cast(unsigned, f);
  unsigned r = (u + 0x7FFFu + ((u >> 16) & 1u)) >> 16;
  return (u16)r;
}
DEV float b2f(u16 h) { return __builtin_bit_cast(float, (unsigned)h << 16); }
DEV f32x4 mfma16(s16x8 a, s16x8 b, f32x4 c) {
  return __builtin_amdgcn_mfma_f32_16x16x32_bf16(a, b, c, 0, 0, 0);
}
DEV float sigmoidf_(float x) { return 1.0f / (1.0f + expf(-x)); }

DEV void g2l16(const u16* g, u16* l) {
  __builtin_amdgcn_global_load_lds((const __attribute__((address_space(1))) void*)g,
                                   (__attribute__((address_space(3))) void*)l, 16, 0, 0);
}

#define BAR() __builtin_amdgcn_s_barrier()
#define WAITV8() asm volatile("s_waitcnt vmcnt(8)" ::: "memory")
#define WAITV4() asm volatile("s_waitcnt vmcnt(4)" ::: "memory")
#define WAITV0() asm volatile("s_waitcnt vmcnt(0)" ::: "memory")
#define WAITL0()                                         \
  do {                                                   \
    asm volatile("s_waitcnt lgkmcnt(0)" ::: "memory");   \
    __builtin_amdgcn_sched_barrier(0);                   \
  } while (0)

// ---------------------------------------------------------------- fused f32->bf16 weight casts
__global__ __launch_bounds__(256) void cast_all(
    const float* __restrict__ Wq, const float* __restrict__ Wk, const float* __restrict__ Wv,
    const float* __restrict__ Wo, const float* __restrict__ adw, const float* __restrict__ auw,
    const float* __restrict__ bdw, const float* __restrict__ buw,
    u16* __restrict__ Wqkvb, u16* __restrict__ Wob, u16* __restrict__ adb,
    u16* __restrict__ aub, u16* __restrict__ bdb, u16* __restrict__ bub) {
  const int b = blockIdx.x;
  const float* s;
  u16* d;
  int rb;
  if (b < 768) {
    s = (b < 256) ? Wq : (b < 512) ? Wk : Wv;
    rb = (b < 256) ? b : (b < 512) ? (b - 256) : (b - 512);
    d = Wqkvb + ((b < 256) ? 0 : (b < 512) ? 262144 : 524288);
  } else if (b < 1024) { s = Wo;  d = Wob; rb = b - 768; }
  else if (b < 1152)   { s = adw; d = adb; rb = b - 1024; }
  else if (b < 1280)   { s = auw; d = aub; rb = b - 1152; }
  else if (b < 3328)   { s = bdw; d = bdb; rb = b - 1280; }
  else                 { s = buw; d = bub; rb = b - 3328; }
  size_t i = ((size_t)rb * 256 + threadIdx.x) * 4;
  float4 v = *(const float4*)(s + i);
  ushort4 p; p.x = f2b(v.x); p.y = f2b(v.y); p.z = f2b(v.z); p.w = f2b(v.w);
  *(ushort4*)(d + i) = p;
}

// ---------------------------------------------------------------- rmsnorm (fp32 in, row = 1024)
__global__ __launch_bounds__(256) void rmsnorm_k(const float* __restrict__ x, u16* __restrict__ y) {
  const size_t row = blockIdx.x;
  const int tid = threadIdx.x;
  float4 v = ((const float4*)(x + row * 1024))[tid];
  float ss = v.x * v.x + v.y * v.y + v.z * v.z + v.w * v.w;
#pragma unroll
  for (int o = 32; o >= 1; o >>= 1) ss += __shfl_xor(ss, o);
  __shared__ float red[4];
  if ((tid & 63) == 0) red[tid >> 6] = ss;
  __syncthreads();
  float tot = red[0] + red[1] + red[2] + red[3];
  float rn = rsqrtf(tot * (1.0f / 1024.0f) + 1.1920929e-7f);
  ushort4 p;
  p.x = f2b(v.x * rn); p.y = f2b(v.y * rn); p.z = f2b(v.z * rn); p.w = f2b(v.w * rn);
  *(ushort4*)(y + row * 1024 + tid * 4) = p;
}

// ---------------------------------------------------------------- rmsnorm (bf16 in, row = 1024)
__global__ __launch_bounds__(256) void rmsnorm_b16(const u16* __restrict__ x, u16* __restrict__ y) {
  const size_t row = blockIdx.x;
  const int tid = threadIdx.x;
  ushort4 h = ((const ushort4*)(x + row * 1024))[tid];
  float v0 = b2f(h.x), v1 = b2f(h.y), v2 = b2f(h.z), v3 = b2f(h.w);
  float ss = v0 * v0 + v1 * v1 + v2 * v2 + v3 * v3;
#pragma unroll
  for (int o = 32; o >= 1; o >>= 1) ss += __shfl_xor(ss, o);
  __shared__ float red[4];
  if ((tid & 63) == 0) red[tid >> 6] = ss;
  __syncthreads();
  float tot = red[0] + red[1] + red[2] + red[3];
  float rn = rsqrtf(tot * (1.0f / 1024.0f) + 1.1920929e-7f);
  ushort4 p;
  p.x = f2b(v0 * rn); p.y = f2b(v1 * rn); p.z = f2b(v2 * rn); p.w = f2b(v3 * rn);
  *(ushort4*)(y + row * 1024 + tid * 4) = p;
}

// ---------------------------------------------------------------- delta (3-phase, 64-chunks)
__global__ __launch_bounds__(256)
void delta_partial(const u16* __restrict__ y, const float* __restrict__ logits, float* __restrict__ Pp) {
  const int v = blockIdx.x * 256 + threadIdx.x;
  const int c = blockIdx.y, b = blockIdx.z;
  const float dec = sigmoidf_(logits[v]);
  const float ldc = logf(fmaxf(dec, 1e-6f));
  const float dc = expf(ldc);
  const u16* yp = y + ((size_t)b * 4096 + c * 64) * 1024 + v;
  float wv = expf((float)(4095 - (c * 64 + 63)) * ldc);
  float acc = 0.0f;
  for (int t = 63; t >= 0; --t) {
    acc += b2f(yp[(size_t)t * 1024]) * wv;
    wv *= dc;
  }
  Pp[((size_t)b * 64 + c) * 1024 + v] = acc;
}

__global__ __launch_bounds__(256) void delta_scan(float* __restrict__ Pp) {
  const int v = blockIdx.x * 256 + threadIdx.x;
  const int b = blockIdx.y;
  float run = 0.0f;
  for (int c = 0; c < 64; ++c) {
    size_t i = ((size_t)b * 64 + c) * 1024 + v;
    float t = Pp[i];
    Pp[i] = run;
    run += t;
  }
}

// writes x1 as bf16 ONLY
__global__ __launch_bounds__(256)
void delta_apply(const float* __restrict__ x0, const u16* __restrict__ y,
                 const float* __restrict__ logits, const float* __restrict__ scale_p,
                 const float* __restrict__ Pp, u16* __restrict__ x1b) {
  const int v = blockIdx.x * 256 + threadIdx.x;
  const int c = blockIdx.y, b = blockIdx.z;
  const float dec = sigmoidf_(logits[v]);
  const float ldc = logf(fmaxf(dec, 1e-6f));
  const float dc = expf(ldc);
  const float invd = expf(-ldc);
  const float sc = scale_p[0];
  float wv = expf((float)(4095 - c * 64) * ldc);
  float iw = expf(-(float)(4095 - c * 64) * ldc);
  float carry = Pp[((size_t)b * 64 + c) * 1024 + v];
  size_t base = ((size_t)b * 4096 + c * 64) * 1024 + v;
  for (int t = 0; t < 64; ++t) {
    size_t idx = base + (size_t)t * 1024;
    float o = x0[idx] + carry * fminf(iw, 1e8f) * sc;
    x1b[idx] = f2b(o);
    carry += b2f(y[idx]) * wv;
    wv *= invd;
    iw *= dc;
  }
}

// ---------------------------------------------------------------- GEMM variant S (m97 single-buffer)
// LDS exactly 32KB -> 5 blocks/CU (was 35KB/4 blocks; EPI5 CT no longer lives here).
// EPI 6: Cb = bf16(Xin + C*scale)        (fp32 residual in, bf16 out)
// EPI 8: Cb = bf16(b2f(Xb16) + C*scale)  (bf16 residual in, bf16 out; in-place safe)
template <int EPI>
__global__ __launch_bounds__(256, 5)
void pgemm_s(const u16* __restrict__ A, const u16* __restrict__ Bw,
             int M, int N, int K,
             u16* __restrict__ Cb,
             const float* __restrict__ Xin, float* __restrict__ Xout,
             const u16* __restrict__ Xb16,
             const float* __restrict__ bias, const float* __restrict__ scale_p) {
  __shared__ u16 sm[16384];  // 32 KB exactly: A[128][64] + B[128][64]; tl overlays
  const int tid = threadIdx.x;
  const int wid = tid >> 6, lane = tid & 63;
  const int gx = gridDim.x;
  const int id = blockIdx.y * gx + blockIdx.x;
  const int q8 = (gx * gridDim.y) >> 3;
  const int nid = (id & 7) * q8 + (id >> 3);
  const int bx = nid % gx, by = nid / gx;
  const int n0 = bx * 128, m0 = by * 128;
  const int wm = (wid >> 1) * 64, wn = (wid & 1) * 64;
  const int lr = lane & 15, lkc = lane >> 4;
  const int sw = lr & 7;
  const int c0 = (lkc ^ sw) * 8, c1 = ((lkc + 4) ^ sw) * 8;
  const int NT = K >> 6;
  const int srow = lane >> 3;
  const int scol = ((lane & 7) ^ srow) * 8;
  const u16* Ag = A + (size_t)(m0 + wid * 8 + srow) * K + scol;
  const u16* Bg = Bw + (size_t)(n0 + wid * 8 + srow) * K + scol;
  u16* const As = sm;
  u16* const Bs = sm + 8192;

  f32x4 acc[4][4] = {};

  for (int t = 0; t < NT; ++t) {
    {
      const u16* ga = Ag + (size_t)t * 64;
      const u16* gb = Bg + (size_t)t * 64;
      u16* la = As + wid * 512;
      u16* lb = Bs + wid * 512;
#pragma unroll
      for (int c = 0; c < 4; ++c) {
        g2l16(ga + (size_t)c * 32 * K, la + c * 2048);
        g2l16(gb + (size_t)c * 32 * K, lb + c * 2048);
      }
    }
    __syncthreads();
    s16x8 af[4][2], bfr[2][2][2];
#pragma unroll
    for (int i = 0; i < 4; ++i) {
      int base = (wm + i * 16 + lr) * 64;
      af[i][0] = *(const s16x8*)&As[base + c0];
      af[i][1] = *(const s16x8*)&As[base + c1];
    }
#pragma unroll
    for (int h = 0; h < 2; ++h)
#pragma unroll
      for (int j = 0; j < 2; ++j) {
        int base = (wn + h * 32 + j * 16 + lr) * 64;
        bfr[h][j][0] = *(const s16x8*)&Bs[base + c0];
        bfr[h][j][1] = *(const s16x8*)&Bs[base + c1];
      }
#pragma unroll
    for (int i = 0; i < 4; ++i)
#pragma unroll
      for (int h = 0; h < 2; ++h)
#pragma unroll
        for (int j = 0; j < 2; ++j) {
          acc[i][h * 2 + j] = mfma16(af[i][0], bfr[h][j][0], acc[i][h * 2 + j]);
          acc[i][h * 2 + j] = mfma16(af[i][1], bfr[h][j][1], acc[i][h * 2 + j]);
        }
    __syncthreads();
  }

  float* tl = (float*)(void*)sm + wid * 1088;
  const float sc = (EPI == 2 || EPI == 6 || EPI == 8) ? scale_p[0] : 0.0f;
  float4 bpf = {0.0f, 0.0f, 0.0f, 0.0f};
  if constexpr (EPI == 3 || EPI == 4) bpf = *(const float4*)&bias[n0 + wn + lr * 4];
#pragma unroll
  for (int i = 0; i < 4; ++i) {
#pragma unroll
    for (int j = 0; j < 4; ++j)
#pragma unroll
      for (int r = 0; r < 4; ++r)
        tl[(lkc * 4 + r) * 68 + j * 16 + lr] = acc[i][j][r];
#pragma unroll
    for (int p = 0; p < 4; ++p) {
      const int row = p * 4 + lkc, nl = lr * 4;
      f32x4 v = *(const f32x4*)&tl[row * 68 + nl];
      const int m = m0 + wm + i * 16 + row;
      const int n = n0 + wn + nl;
      const size_t idx = (size_t)m * N + n;
      if constexpr (EPI == 0) {
        ushort4 o = {f2b(v[0]), f2b(v[1]), f2b(v[2]), f2b(v[3])};
        *(ushort4*)&Cb[idx] = o;
      } else if constexpr (EPI == 2) {
        float4 x = *(const float4*)&Xin[idx];
        float4 o = {x.x + v[0] * sc, x.y + v[1] * sc, x.z + v[2] * sc, x.w + v[3] * sc};
        *(float4*)&Xout[idx] = o;
      } else if constexpr (EPI == 6) {
        float4 x = *(const float4*)&Xin[idx];
        ushort4 o = {f2b(x.x + v[0] * sc), f2b(x.y + v[1] * sc),
                     f2b(x.z + v[2] * sc), f2b(x.w + v[3] * sc)};
        *(ushort4*)&Cb[idx] = o;
      } else if constexpr (EPI == 8) {
        ushort4 hx = *(const ushort4*)&Xb16[idx];
        ushort4 o = {f2b(b2f(hx.x) + v[0] * sc), f2b(b2f(hx.y) + v[1] * sc),
                     f2b(b2f(hx.z) + v[2] * sc), f2b(b2f(hx.w) + v[3] * sc)};
        *(ushort4*)&Cb[idx] = o;
      } else if constexpr (EPI == 3) {
        float g0 = v[0] + bpf.x, g1 = v[1] + bpf.y, g2 = v[2] + bpf.z, g3 = v[3] + bpf.w;
        ushort4 o;
        o.x = f2b(g0 * sigmoidf_(1.59576912f * fmaf(0.044715f * g0, g0 * g0, g0)));
        o.y = f2b(g1 * sigmoidf_(1.59576912f * fmaf(0.044715f * g1, g1 * g1, g1)));
        o.z = f2b(g2 * sigmoidf_(1.59576912f * fmaf(0.044715f * g2, g2 * g2, g2)));
        o.w = f2b(g3 * sigmoidf_(1.59576912f * fmaf(0.044715f * g3, g3 * g3, g3)));
        *(ushort4*)&Cb[idx] = o;
      } else {
        float4 x = *(const float4*)&Xin[idx];
        float4 o = {x.x * sigmoidf_(v[0] + bpf.x), x.y * sigmoidf_(v[1] + bpf.y),
                    x.z * sigmoidf_(v[2] + bpf.z), x.w * sigmoidf_(v[3] + bpf.w)};
        *(float4*)&Xout[idx] = o;
      }
    }
  }
}

// ---------------------------------------------------------------- GEMM variant D (dbuf, full EPI set)
// EPI 7: gate = sigmoid(C+bias); Xb16 = bf16(b2f(P1)*gate); optional fp32 Xout
// EPI 8: Cb = bf16(b2f(P1) + C*scale)
// EPI 9: Xout = b2f(P1) + C*scale (fp32 out)
template <int EPI>
__global__ __launch_bounds__(256, 2)
void pgemm_d(const u16* __restrict__ A, const u16* __restrict__ Bw,
             int M, int N, int K,
             u16* __restrict__ Cb,
             const float* __restrict__ Xin, float* __restrict__ Xout,
             u16* __restrict__ Xb16,
             const float* __restrict__ bias, const float* __restrict__ scale_p,
             u16* __restrict__ P1, u16* __restrict__ P2, u16* __restrict__ P3) {
  __shared__ u16 sm[32768];
  const int tid = threadIdx.x;
  const int wid = tid >> 6, lane = tid & 63;
  const int gx = gridDim.x;
  const int id = blockIdx.y * gx + blockIdx.x;
  const int q8 = (gx * gridDim.y) >> 3;
  const int nid = (id & 7) * q8 + (id >> 3);
  const int bx = nid % gx, by = nid / gx;
  const int n0 = bx * 128, m0 = by * 128;
  const int wm = (wid >> 1) * 64, wn = (wid & 1) * 64;
  const int lr = lane & 15, lkc = lane >> 4;
  const int sw = lr & 7;
  const int c0 = (lkc ^ sw) * 8, c1 = ((lkc + 4) ^ sw) * 8;
  const int NT = K >> 6;
  const int srow = lane >> 3;
  const int scol = ((lane & 7) ^ srow) * 8;
  const u16* Ag = A + (size_t)(m0 + wid * 8 + srow) * K + scol;
  const u16* Bg = Bw + (size_t)(n0 + wid * 8 + srow) * K + scol;
  u16* const AL0 = sm;          u16* const BL0 = sm + 8192;
  u16* const AL1 = sm + 16384;  u16* const BL1 = sm + 24576;

  f32x4 acc[4][4] = {};

  auto STA = [&](int tau) {
    const u16* g = Ag + (size_t)tau * 64;
    u16* l = ((tau & 1) ? AL1 : AL0) + wid * 512;
#pragma unroll
    for (int c = 0; c < 4; ++c) g2l16(g + (size_t)c * 32 * K, l + c * 2048);
  };
  auto STB = [&](int tau) {
    const u16* g = Bg + (size_t)tau * 64;
    u16* l = ((tau & 1) ? BL1 : BL0) + wid * 512;
#pragma unroll
    for (int c = 0; c < 4; ++c) g2l16(g + (size_t)c * 32 * K, l + c * 2048);
  };
  auto RDA = [&](int tau, s16x8 (&d)[4][2]) {
    const u16* Ab = (tau & 1) ? AL1 : AL0;
#pragma unroll
    for (int i = 0; i < 4; ++i) {
      int base = (wm + i * 16 + lr) * 64;
      d[i][0] = *(const s16x8*)&Ab[base + c0];
      d[i][1] = *(const s16x8*)&Ab[base + c1];
    }
  };
  auto RDB = [&](int tau, int h, s16x8 (&d)[2][2]) {
    const u16* Bb = (tau & 1) ? BL1 : BL0;
#pragma unroll
    for (int j = 0; j < 2; ++j) {
      int base = (wn + h * 32 + j * 16 + lr) * 64;
      d[j][0] = *(const s16x8*)&Bb[base + c0];
      d[j][1] = *(const s16x8*)&Bb[base + c1];
    }
  };
  auto MM = [&](s16x8 (&Ar)[4][2], s16x8 (&Br)[2][2], int jo) {
    __builtin_amdgcn_s_setprio(1);
#pragma unroll
    for (int i = 0; i < 4; ++i)
#pragma unroll
      for (int j = 0; j < 2; ++j) {
        acc[i][jo + j] = mfma16(Ar[i][0], Br[j][0], acc[i][jo + j]);
        acc[i][jo + j] = mfma16(Ar[i][1], Br[j][1], acc[i][jo + j]);
      }
    __builtin_amdgcn_s_setprio(0);
  };

  s16x8 Ae[4][2], Ao[4][2], B0r[2][2], B1r[2][2];
  STA(0); STB(0);
  if (NT > 1) { STA(1); STB(1); }
  WAITV8(); BAR();
  RDA(0, Ae); RDB(0, 0, B0r);

  for (int t = 0; t < NT; t += 2) {
    RDB(t, 1, B1r);
    if (t + 2 < NT) STA(t + 2);
    BAR(); WAITL0();
    MM(Ae, B0r, 0);
    BAR();
    if (t + 2 < NT) { STB(t + 2); WAITV8(); } else { WAITV0(); }
    BAR();
    if (t + 1 < NT) { RDA(t + 1, Ao); RDB(t + 1, 0, B0r); }
    WAITL0();
    MM(Ae, B1r, 2);
    BAR();
    if (t + 1 >= NT) break;
    RDB(t + 1, 1, B1r);
    if (t + 3 < NT) STA(t + 3);
    BAR(); WAITL0();
    MM(Ao, B0r, 0);
    BAR();
    if (t + 3 < NT) { STB(t + 3); WAITV8(); } else { WAITV0(); }
    BAR();
    if (t + 2 < NT) { RDA(t + 2, Ae); RDB(t + 2, 0, B0r); }
    WAITL0();
    MM(Ao, B1r, 2);
    BAR();
  }

  float* tl = (float*)(void*)sm + wid * 1088;

  if constexpr (EPI == 5) {
    if (bx < 4) {
      u16* dst = (bx < 2) ? Cb : P1;
      const int nb = (bx & 1) * 128;
#pragma unroll
      for (int i = 0; i < 4; ++i) {
#pragma unroll
        for (int j = 0; j < 4; ++j)
#pragma unroll
          for (int r = 0; r < 4; ++r)
            tl[(lkc * 4 + r) * 68 + j * 16 + lr] = acc[i][j][r];
#pragma unroll
        for (int p = 0; p < 4; ++p) {
          const int row = p * 4 + lkc, nl = lr * 4;
          f32x4 v = *(const f32x4*)&tl[row * 68 + nl];
          const int m = m0 + wm + i * 16 + row;
          ushort4 o = {f2b(v[0]), f2b(v[1]), f2b(v[2]), f2b(v[3])};
          *(ushort4*)&dst[(size_t)m * 256 + nb + wn + nl] = o;
        }
      }
      if (bx >= 2) {
        const float ld5 = logf(sigmoidf_(scale_p[0]));
        u16* CT = sm;
        __syncthreads();
#pragma unroll
        for (int i = 0; i < 4; ++i)
#pragma unroll
          for (int j = 0; j < 4; ++j)
#pragma unroll
            for (int r = 0; r < 4; ++r) {
              int ml = wm + i * 16 + lkc * 4 + r;
              int nl = wn + j * 16 + lr;
              float g = expf(ld5 * (float)(ml & 63));
              CT[nl * 136 + ml] = f2b(acc[i][j][r] * g);
            }
        __syncthreads();
        int d = tid >> 1, off = (tid & 1) * 64;
        size_t base = ((size_t)(m0 >> 12) * 256 + (bx - 2) * 128 + d) * 4096 + (m0 & 4095) + off;
#pragma unroll
        for (int p = 0; p < 8; ++p)
          *(uint4*)&P3[base + p * 8] = *(const uint4*)&CT[d * 136 + off + p * 8];
      }
    } else {
      u16* CT = sm;
      __syncthreads();
#pragma unroll
      for (int i = 0; i < 4; ++i)
#pragma unroll
        for (int j = 0; j < 4; ++j)
#pragma unroll
          for (int r = 0; r < 4; ++r) {
            int ml = wm + i * 16 + lkc * 4 + r;
            int nl = wn + j * 16 + lr;
            CT[nl * 136 + ml] = f2b(acc[i][j][r]);
          }
      __syncthreads();
      int d = tid >> 1, off = (tid & 1) * 64;
      size_t base = ((size_t)(m0 >> 12) * 256 + (bx - 4) * 128 + d) * 4096 + (m0 & 4095) + off;
#pragma unroll
      for (int p = 0; p < 8; ++p)
        *(uint4*)&P2[base + p * 8] = *(const uint4*)&CT[d * 136 + off + p * 8];
    }
  } else {
    const float sc = (EPI == 2 || EPI == 6 || EPI == 8 || EPI == 9) ? scale_p[0] : 0.0f;
    float4 bpf = {0.0f, 0.0f, 0.0f, 0.0f};
    if constexpr (EPI == 3 || EPI == 4 || EPI == 7) bpf = *(const float4*)&bias[n0 + wn + lr * 4];
#pragma unroll
    for (int i = 0; i < 4; ++i) {
#pragma unroll
      for (int j = 0; j < 4; ++j)
#pragma unroll
        for (int r = 0; r < 4; ++r)
          tl[(lkc * 4 + r) * 68 + j * 16 + lr] = acc[i][j][r];
#pragma unroll
      for (int p = 0; p < 4; ++p) {
        const int row = p * 4 + lkc, nl = lr * 4;
        f32x4 v = *(const f32x4*)&tl[row * 68 + nl];
        const int m = m0 + wm + i * 16 + row;
        const int n = n0 + wn + nl;
        const size_t idx = (size_t)m * N + n;
        if constexpr (EPI == 0) {
          ushort4 o = {f2b(v[0]), f2b(v[1]), f2b(v[2]), f2b(v[3])};
          *(ushort4*)&Cb[idx] = o;
        } else if constexpr (EPI == 2) {
          float4 x = *(const float4*)&Xin[idx];
          float4 o = {x.x + v[0] * sc, x.y + v[1] * sc, x.z + v[2] * sc, x.w + v[3] * sc};
          *(float4*)&Xout[idx] = o;
          if (Xb16) {
            ushort4 ob = {f2b(o.x), f2b(o.y), f2b(o.z), f2b(o.w)};
            *(ushort4*)&Xb16[idx] = ob;
          }
        } else if constexpr (EPI == 6) {
          float4 x = *(const float4*)&Xin[idx];
          ushort4 o = {f2b(x.x + v[0] * sc), f2b(x.y + v[1] * sc),
                       f2b(x.z + v[2] * sc), f2b(x.w + v[3] * sc)};
          *(ushort4*)&Cb[idx] = o;
        } else if constexpr (EPI == 8) {
          ushort4 hx = *(const ushort4*)&P1[idx];
          ushort4 o = {f2b(b2f(hx.x) + v[0] * sc), f2b(b2f(hx.y) + v[1] * sc),
                       f2b(b2f(hx.z) + v[2] * sc), f2b(b2f(hx.w) + v[3] * sc)};
          *(ushort4*)&Cb[idx] = o;
        } else if constexpr (EPI == 9) {
          ushort4 hx = *(const ushort4*)&P1[idx];
          float4 o = {b2f(hx.x) + v[0] * sc, b2f(hx.y) + v[1] * sc,
                      b2f(hx.z) + v[2] * sc, b2f(hx.w) + v[3] * sc};
          *(float4*)&Xout[idx] = o;
        } else if constexpr (EPI == 3) {
          float g0 = v[0] + bpf.x, g1 = v[1] + bpf.y, g2 = v[2] + bpf.z, g3 = v[3] + bpf.w;
          ushort4 o;
          o.x = f2b(g0 * sigmoidf_(1.59576912f * fmaf(0.044715f * g0, g0 * g0, g0)));
          o.y = f2b(g1 * sigmoidf_(1.59576912f * fmaf(0.044715f * g1, g1 * g1, g1)));
          o.z = f2b(g2 * sigmoidf_(1.59576912f * fmaf(0.044715f * g2, g2 * g2, g2)));
          o.w = f2b(g3 * sigmoidf_(1.59576912f * fmaf(0.044715f * g3, g3 * g3, g3)));
          *(ushort4*)&Cb[idx] = o;
        } else if constexpr (EPI == 4) {
          float4 x = *(const float4*)&Xin[idx];
          float4 o = {x.x * sigmoidf_(v[0] + bpf.x), x.y * sigmoidf_(v[1] + bpf.y),
                      x.z * sigmoidf_(v[2] + bpf.z), x.w * sigmoidf_(v[3] + bpf.w)};
          *(float4*)&Xout[idx] = o;
          if (Xb16) {
            ushort4 ob = {f2b(o.x), f2b(o.y), f2b(o.z), f2b(o.w)};
            *(ushort4*)&Xb16[idx] = ob;
          }
        } else {  // EPI 7
          ushort4 hx = *(const ushort4*)&P1[idx];
          float4 o = {b2f(hx.x) * sigmoidf_(v[0] + bpf.x), b2f(hx.y) * sigmoidf_(v[1] + bpf.y),
                      b2f(hx.z) * sigmoidf_(v[2] + bpf.z), b2f(hx.w) * sigmoidf_(v[3] + bpf.w)};
          if (Xout) *(float4*)&Xout[idx] = o;
          ushort4 ob = {f2b(o.x), f2b(o.y), f2b(o.z), f2b(o.w)};
          *(ushort4*)&Xb16[idx] = ob;
        }
      }
    }
  }
}

// ---------------------------------------------------------------- chunked linear attention (bf16 G)
__global__ __launch_bounds__(256, 2)
void chunk_G(const u16* __restrict__ vT, const u16* __restrict__ kTs, u16* __restrict__ Gp) {
  __shared__ u16 sm2[16384];
  const int c = blockIdx.x, eh = blockIdx.y >> 1, dh = blockIdx.y & 1, b = blockIdx.z;
  const int tid = threadIdx.x, wid = tid >> 6, lane = tid & 63;
  u16* AL = sm2; u16* BL = sm2 + 8192;
  const u16* As = vT + (size_t)(b * 256 + eh * 128) * 4096 + c * 64;
  const u16* Bs = kTs + (size_t)(b * 256 + dh * 128) * 4096 + c * 64;
  const int r8 = lane >> 3, sc8 = ((lane & 7) ^ (lane >> 3)) * 8;
#pragma unroll
  for (int p = 0; p < 4; ++p) {
    int ch = p * 4 + wid;
    int row = ch * 8 + r8;
    g2l16(As + (size_t)row * 4096 + sc8, AL + ch * 512);
    g2l16(Bs + (size_t)row * 4096 + sc8, BL + ch * 512);
  }
  __syncthreads();
  const int wm = (wid >> 1) * 64, wn = (wid & 1) * 64;
  const int lr = lane & 15, lkc = lane >> 4, sw = lr & 7;
  const int c0 = (lkc ^ sw) * 8, c1 = ((lkc + 4) ^ sw) * 8;
  s16x8 af[4][2], bf[4][2];
#pragma unroll
  for (int i = 0; i < 4; ++i) {
    int ba = (wm + i * 16 + lr) * 64;
    af[i][0] = *(const s16x8*)&AL[ba + c0];
    af[i][1] = *(const s16x8*)&AL[ba + c1];
    int bb = (wn + i * 16 + lr) * 64;
    bf[i][0] = *(const s16x8*)&BL[bb + c0];
    bf[i][1] = *(const s16x8*)&BL[bb + c1];
  }
  f32x4 acc[4][4] = {};
#pragma unroll
  for (int i = 0; i < 4; ++i)
#pragma unroll
    for (int j = 0; j < 4; ++j) {
      acc[i][j] = mfma16(af[i][0], bf[j][0], acc[i][j]);
      acc[i][j] = mfma16(af[i][1], bf[j][1], acc[i][j]);
    }
  u16* Gb = Gp + (size_t)(b * 64 + c) * 65536;
#pragma unroll
  for (int i = 0; i < 4; ++i)
#pragma unroll
    for (int j = 0; j < 4; ++j)
#pragma unroll
      for (int r = 0; r < 4; ++r) {
        int e = eh * 128 + wm + i * 16 + lkc * 4 + r;
        int d = dh * 128 + wn + j * 16 + lr;
        Gb[(size_t)e * 256 + d] = f2b(acc[i][j][r]);
      }
}

// M_c = G'_{c+1} + gamma^64 * M_{c+1}; M_63 = 0.  4-deep load pipeline.
__global__ __launch_bounds__(256)
void scan_M(const u16* __restrict__ Gp, u16* __restrict__ Mb, const float* __restrict__ dlogit) {
  const int b = blockIdx.y;
  const size_t idx = (size_t)blockIdx.x * 256 + threadIdx.x;
  const float ld = logf(sigmoidf_(dlogit[0]));
  const float g64 = expf(64.0f * ld);
  const u16* G = Gp + (size_t)b * 64 * 65536 + idx;
  u16* M = Mb + (size_t)b * 64 * 65536 + idx;
  const size_t S = 65536;
  float m = 0.0f;
  M[(size_t)63 * S] = 0;
  int c = 62;
  for (; c >= 3; c -= 4) {
    u16 h0 = G[(size_t)(c + 1) * S];
    u16 h1 = G[(size_t)c * S];
    u16 h2 = G[(size_t)(c - 1) * S];
    u16 h3 = G[(size_t)(c - 2) * S];
    m = b2f(h0) + g64 * m; M[(size_t)c * S] = f2b(m);
    m = b2f(h1) + g64 * m; M[(size_t)(c - 1) * S] = f2b(m);
    m = b2f(h2) + g64 * m; M[(size_t)(c - 2) * S] = f2b(m);
    m = b2f(h3) + g64 * m; M[(size_t)(c - 3) * S] = f2b(m);
  }
  for (; c >= 0; --c) {
    m = b2f(G[(size_t)(c + 1) * S]) + g64 * m;
    M[(size_t)c * S] = f2b(m);
  }
}

__global__ __launch_bounds__(256, 2)
void chunk_R(const u16* __restrict__ q, const u16* __restrict__ k,
             const u16* __restrict__ vT, const u16* __restrict__ Mb,
             u16* __restrict__ R, const float* __restrict__ dlogit) {
  __shared__ u16 qL[16384];
  __shared__ u16 shA[16384];
  const int c = blockIdx.x, eh = blockIdx.y, b = blockIdx.z;
  const int tid = threadIdx.x, wid = tid >> 6, lane = tid & 63;
  const float ld = logf(sigmoidf_(dlogit[0]));
  const int r8 = lane >> 3, sc8 = ((lane & 7) ^ (lane >> 3)) * 8;
  const int lr = lane & 15, lkc = lane >> 4, g4 = lkc * 4;
  const int sw = lr & 7;
  const int c0 = (lkc ^ sw) * 8, c1 = ((lkc + 4) ^ sw) * 8;

  const u16* qsrc = q + ((size_t)b * 4096 + c * 64) * 256;
  const u16* ksrc = k + ((size_t)b * 4096 + c * 64) * 256;
  const u16* msrc = Mb + ((size_t)(b * 64 + c) * 256 + eh * 128) * 256;
  const u16* vsrc = vT + (size_t)(b * 256 + eh * 128) * 4096 + c * 64;

#pragma unroll
  for (int kt = 0; kt < 4; ++kt)
#pragma unroll
    for (int p = 0; p < 2; ++p) {
      int ch = p * 4 + wid;
      int row = ch * 8 + r8;
      g2l16(qsrc + (size_t)row * 256 + kt * 64 + sc8, qL + kt * 4096 + ch * 512);
    }
#pragma unroll
  for (int p = 0; p < 4; ++p) {
    int ch = p * 4 + wid;
    int row = ch * 8 + r8;
    g2l16(msrc + (size_t)row * 256 + sc8, shA + ch * 512);
  }
  f32x4 accx[4][2] = {};
  for (int dt = 0; dt < 4; ++dt) {
    if (dt < 3) {
      u16* dst = shA + ((dt + 1) & 1) * 8192;
#pragma unroll
      for (int p = 0; p < 4; ++p) {
        int ch = p * 4 + wid;
        int row = ch * 8 + r8;
        g2l16(msrc + (size_t)row * 256 + (dt + 1) * 64 + sc8, dst + ch * 512);
      }
      WAITV4();
    } else {
      WAITV0();
    }
    BAR();
    const u16* mt = shA + (dt & 1) * 8192;
    const u16* qt = qL + dt * 4096;
    s16x8 aq[4][2], bm[2][2];
#pragma unroll
    for (int i = 0; i < 4; ++i) {
      int ba = (i * 16 + lr) * 64;
      aq[i][0] = *(const s16x8*)&qt[ba + c0];
      aq[i][1] = *(const s16x8*)&qt[ba + c1];
    }
#pragma unroll
    for (int j = 0; j < 2; ++j) {
      int ba = (wid * 32 + j * 16 + lr) * 64;
      bm[j][0] = *(const s16x8*)&mt[ba + c0];
      bm[j][1] = *(const s16x8*)&mt[ba + c1];
    }
#pragma unroll
    for (int i = 0; i < 4; ++i)
#pragma unroll
      for (int j = 0; j < 2; ++j) {
        accx[i][j] = mfma16(aq[i][0], bm[j][0], accx[i][j]);
        accx[i][j] = mfma16(aq[i][1], bm[j][1], accx[i][j]);
      }
    BAR();
  }
#pragma unroll
  for (int kt = 0; kt < 4; ++kt)
#pragma unroll
    for (int p = 0; p < 2; ++p) {
      int ch = p * 4 + wid;
      int row = ch * 8 + r8;
      g2l16(ksrc + (size_t)row * 256 + kt * 64 + sc8, shA + kt * 4096 + ch * 512);
    }
  __syncthreads();
  f32x4 accs[4] = {};
#pragma unroll
  for (int kt = 0; kt < 4; ++kt) {
    const u16* qt = qL + kt * 4096;
    const u16* klt = shA + kt * 4096;
    s16x8 aq[4][2], bk[2];
#pragma unroll
    for (int i = 0; i < 4; ++i) {
      int ba = (i * 16 + lr) * 64;
      aq[i][0] = *(const s16x8*)&qt[ba + c0];
      aq[i][1] = *(const s16x8*)&qt[ba + c1];
    }
    {
      int ba = (wid * 16 + lr) * 64;
      bk[0] = *(const s16x8*)&klt[ba + c0];
      bk[1] = *(const s16x8*)&klt[ba + c1];
    }
#pragma unroll
    for (int i = 0; i < 4; ++i) {
      accs[i] = mfma16(aq[i][0], bk[0], accs[i]);
      accs[i] = mfma16(aq[i][1], bk[1], accs[i]);
    }
  }
  __syncthreads();
  u16* PL = shA;
  u16* vTL = shA + 4608;
#pragma unroll
  for (int p = 0; p < 4; ++p) {
    int ch = p * 4 + wid;
    int row = ch * 8 + r8;
    g2l16(vsrc + (size_t)row * 4096 + sc8, vTL + ch * 512);
  }
#pragma unroll
  for (int i = 0; i < 4; ++i)
#pragma unroll
    for (int r = 0; r < 4; ++r) {
      int gi = i * 16 + g4 + r;
      int gj = wid * 16 + lr;
      float pw = (gj > gi) ? expf(ld * (float)(gj - gi - 1)) : 0.0f;
      PL[gi * 72 + gj] = f2b(accs[i][r] * pw);
    }
  __syncthreads();
  f32x4 acci[4][2] = {};
  {
    s16x8 pa[4][2], bv[2][2];
#pragma unroll
    for (int i = 0; i < 4; ++i) {
      pa[i][0] = *(const s16x8*)&PL[(i * 16 + lr) * 72 + lkc * 8];
      pa[i][1] = *(const s16x8*)&PL[(i * 16 + lr) * 72 + 32 + lkc * 8];
    }
#pragma unroll
    for (int j = 0; j < 2; ++j) {
      int ba = (wid * 32 + j * 16 + lr) * 64;
      bv[j][0] = *(const s16x8*)&vTL[ba + c0];
      bv[j][1] = *(const s16x8*)&vTL[ba + c1];
    }
#pragma unroll
    for (int i = 0; i < 4; ++i)
#pragma unroll
      for (int j = 0; j < 2; ++j) {
        acci[i][j] = mfma16(pa[i][0], bv[j][0], acci[i][j]);
        acci[i][j] = mfma16(pa[i][1], bv[j][1], acci[i][j]);
      }
  }
  u16* Ro = R + ((size_t)b * 4096 + c * 64) * 256 + eh * 128;
#pragma unroll
  for (int i = 0; i < 4; ++i)
#pragma unroll
    for (int r = 0; r < 4; ++r) {
      int gi = i * 16 + g4 + r;
      float xf = expf(ld * (float)(63 - gi));
#pragma unroll
      for (int j = 0; j < 2; ++j) {
        int ge = wid * 32 + j * 16 + lr;
        Ro[(size_t)gi * 256 + ge] = f2b(acci[i][j][r] + xf * accx[i][j][r]);
      }
    }
}

// ---------------------------------------------------------------- host
extern "C" void kernel_launch(void* const* d_in, const int* in_sizes, int n_in,
                              void* d_out, int out_size, void* d_ws, size_t ws_size,
                              hipStream_t stream) {
  const float* x0 = (const float*)d_in[0];
  const float* Wq = (const float*)d_in[1];
  const float* Wk = (const float*)d_in[2];
  const float* Wv = (const float*)d_in[3];
  const float* Wo = (const float*)d_in[4];
  const float* dlog = (const float*)d_in[5];
  const float* dscale = (const float*)d_in[6];
  const float* th_dec = (const float*)d_in[7];
  const float* th_sc = (const float*)d_in[8];
  const float* ga_dec = (const float*)d_in[9];
  const float* ga_sc = (const float*)d_in[10];
  const float* adw = (const float*)d_in[11];
  const float* auw = (const float*)d_in[12];
  const float* a_upb = (const float*)d_in[13];
  const float* bdw = (const float*)d_in[14];
  const float* buw = (const float*)d_in[15];
  const float* bbias = (const float*)d_in[16];
  const float* bscale = (const float*)d_in[17];

  char* w = (char*)d_ws;
  float* xA = (float*)w;                       // 33,554,432 (kT scratch stages 2/5)
  u16* y = (u16*)(w + 33554432);               // 16,777,216 -> M buffer during attn
  u16* xb = (u16*)(w + 50331648);              // 16,777,216 (bf16 residual chain x1..x4)
  u16* qb = (u16*)(w + 67108864);              // 4,194,304
  u16* kb = (u16*)(w + 71303168);              // 4,194,304
  u16* vT = (u16*)(w + 75497472);              // 4,194,304
  u16* Rb = (u16*)(w + 79691776);              // 4,194,304
  u16* gb = (u16*)(w + 83886080);              // 2,097,152  (also Pp during stage 1)
  u16* hb = (u16*)(w + 85983232);              // 33,554,432 -> G (bf16) during attn
  u16* Gp = hb;
  u16* Mbuf = y;
  u16* kTs2 = (u16*)xA;
  u16* kTs5 = (u16*)xA;
  float* Pp = (float*)gb;
  u16* Wqkvb = (u16*)(w + 119799808);          // 1,572,864
  u16* Wob = (u16*)(w + 121372672);            // 524,288
  u16* adb = (u16*)(w + 121896960);            // 262,144
  u16* aub = (u16*)(w + 122159104);            // 262,144
  u16* bdb = (u16*)(w + 122421248);            // 4,194,304
  u16* bub = (u16*)(w + 126615552);            // 4,194,304
  float* xB = (float*)d_out;

  cast_all<<<5376, 256, 0, stream>>>(Wq, Wk, Wv, Wo, adw, auw, bdw, buw,
                                     Wqkvb, Wob, adb, aub, bdb, bub);

  // ---- stage 1: x1 = x0 + delta(rmsnorm(x0))   (bf16 only -> xb)
  rmsnorm_k<<<8192, 256, 0, stream>>>(x0, y);
  delta_partial<<<dim3(4, 64, 2), 256, 0, stream>>>(y, dlog, Pp);
  delta_scan<<<dim3(4, 2), 256, 0, stream>>>(Pp);
  delta_apply<<<dim3(4, 64, 2), 256, 0, stream>>>(x0, y, dlog, dscale, Pp, xb);

  // ---- stage 2: x2 = x1 + memory(rmsnorm(x1), theta)   (EPI8: bf16 in-place on xb)
  rmsnorm_b16<<<8192, 256, 0, stream>>>(xb, y);
  pgemm_d<5><<<dim3(6, 64), 256, 0, stream>>>(y, Wqkvb, 8192, 768, 1024, qb, nullptr, nullptr, nullptr, nullptr, th_dec, kb, vT, kTs2);
  chunk_G<<<dim3(64, 4, 2), 256, 0, stream>>>(vT, kTs2, Gp);
  scan_M<<<dim3(256, 2), 256, 0, stream>>>(Gp, Mbuf, th_dec);
  chunk_R<<<dim3(64, 2, 2), 256, 0, stream>>>(qb, kb, vT, Mbuf, Rb, th_dec);
  pgemm_d<8><<<dim3(8, 64), 256, 0, stream>>>(Rb, Wob, 8192, 1024, 256, xb, nullptr, nullptr, nullptr, nullptr, th_sc, xb, nullptr, nullptr);

  // ---- stage 3: x3 = alpha(x2)   (bf16 only -> xb)
  pgemm_d<0><<<dim3(1, 64), 256, 0, stream>>>(xb, adb, 8192, 128, 1024, gb, nullptr, nullptr, nullptr, nullptr, nullptr, nullptr, nullptr, nullptr);
  pgemm_d<7><<<dim3(8, 64), 256, 0, stream>>>(gb, aub, 8192, 1024, 128, nullptr, nullptr, nullptr, xb, a_upb, nullptr, xb, nullptr, nullptr);

  // ---- stage 4: x4 = x3 + beta(rmsnorm(x3))   (EPI8: bf16 residual from xb, in-place)
  rmsnorm_b16<<<8192, 256, 0, stream>>>(xb, y);
  pgemm_s<3><<<dim3(16, 64), 256, 0, stream>>>(y, bdb, 8192, 2048, 1024, hb, nullptr, nullptr, nullptr, bbias, nullptr);
  pgemm_s<8><<<dim3(8, 64), 256, 0, stream>>>(hb, bub, 8192, 1024, 2048, xb, nullptr, nullptr, xb, nullptr, bscale);

  // ---- stage 5: out = x4 + memory(rmsnorm(x4), gamma)   (kT -> xA scratch; xb preserved)
  rmsnorm_b16<<<8192, 256, 0, stream>>>(xb, y);
  pgemm_d<5><<<dim3(6, 64), 256, 0, stream>>>(y, Wqkvb, 8192, 768, 1024, qb, nullptr, nullptr, nullptr, nullptr, ga_dec, kb, vT, kTs5);
  chunk_G<<<dim3(64, 4, 2), 256, 0, stream>>>(vT, kTs5, Gp);
  scan_M<<<dim3(256, 2), 256, 0, stream>>>(Gp, Mbuf, ga_dec);
  chunk_R<<<dim3(64, 2, 2), 256, 0, stream>>>(qb, kb, vT, Mbuf, Rb, ga_dec);
  pgemm_d<9><<<dim3(8, 64), 256, 0, stream>>>(Rb, Wob, 8192, 1024, 256, nullptr, nullptr, xB, nullptr, nullptr, ga_sc, xb, nullptr, nullptr);
}

// Round 23
// 291.744 us; speedup vs baseline: 1.3640x; 1.3640x over previous
//
#include <hip/hip_runtime.h>

typedef __attribute__((ext_vector_type(8))) short s16x8;
typedef __attribute__((ext_vector_type(4))) float f32x4;
typedef unsigned short u16;

#define DEV __device__ __forceinline__

DEV u16 f2b(float f) {
  unsigned u = __builtin_bit_cast(unsigned, f);
  unsigned r = (u + 0x7FFFu + ((u >> 16) & 1u)) >> 16;
  return (u16)r;
}
DEV float b2f(u16 h) { return __builtin_bit_cast(float, (unsigned)h << 16); }
DEV f32x4 mfma16(s16x8 a, s16x8 b, f32x4 c) {
  return __builtin_amdgcn_mfma_f32_16x16x32_bf16(a, b, c, 0, 0, 0);
}
DEV float sigmoidf_(float x) { return 1.0f / (1.0f + expf(-x)); }

DEV void g2l16(const u16* g, u16* l) {
  __builtin_amdgcn_global_load_lds((const __attribute__((address_space(1))) void*)g,
                                   (__attribute__((address_space(3))) void*)l, 16, 0, 0);
}

#define BAR() __builtin_amdgcn_s_barrier()
#define WAITV8() asm volatile("s_waitcnt vmcnt(8)" ::: "memory")
#define WAITV4() asm volatile("s_waitcnt vmcnt(4)" ::: "memory")
#define WAITV0() asm volatile("s_waitcnt vmcnt(0)" ::: "memory")
#define WAITL0()                                         \
  do {                                                   \
    asm volatile("s_waitcnt lgkmcnt(0)" ::: "memory");   \
    __builtin_amdgcn_sched_barrier(0);                   \
  } while (0)

// ---------------------------------------------------------------- fused f32->bf16 weight casts
__global__ __launch_bounds__(256) void cast_all(
    const float* __restrict__ Wq, const float* __restrict__ Wk, const float* __restrict__ Wv,
    const float* __restrict__ Wo, const float* __restrict__ adw, const float* __restrict__ auw,
    const float* __restrict__ bdw, const float* __restrict__ buw,
    u16* __restrict__ Wqkvb, u16* __restrict__ Wob, u16* __restrict__ adb,
    u16* __restrict__ aub, u16* __restrict__ bdb, u16* __restrict__ bub) {
  const int b = blockIdx.x;
  const float* s;
  u16* d;
  int rb;
  if (b < 768) {
    s = (b < 256) ? Wq : (b < 512) ? Wk : Wv;
    rb = (b < 256) ? b : (b < 512) ? (b - 256) : (b - 512);
    d = Wqkvb + ((b < 256) ? 0 : (b < 512) ? 262144 : 524288);
  } else if (b < 1024) { s = Wo;  d = Wob; rb = b - 768; }
  else if (b < 1152)   { s = adw; d = adb; rb = b - 1024; }
  else if (b < 1280)   { s = auw; d = aub; rb = b - 1152; }
  else if (b < 3328)   { s = bdw; d = bdb; rb = b - 1280; }
  else                 { s = buw; d = bub; rb = b - 3328; }
  size_t i = ((size_t)rb * 256 + threadIdx.x) * 4;
  float4 v = *(const float4*)(s + i);
  ushort4 p; p.x = f2b(v.x); p.y = f2b(v.y); p.z = f2b(v.z); p.w = f2b(v.w);
  *(ushort4*)(d + i) = p;
}

// ---------------------------------------------------------------- rmsnorm (fp32 in, row = 1024)
__global__ __launch_bounds__(256) void rmsnorm_k(const float* __restrict__ x, u16* __restrict__ y) {
  const size_t row = blockIdx.x;
  const int tid = threadIdx.x;
  float4 v = ((const float4*)(x + row * 1024))[tid];
  float ss = v.x * v.x + v.y * v.y + v.z * v.z + v.w * v.w;
#pragma unroll
  for (int o = 32; o >= 1; o >>= 1) ss += __shfl_xor(ss, o);
  __shared__ float red[4];
  if ((tid & 63) == 0) red[tid >> 6] = ss;
  __syncthreads();
  float tot = red[0] + red[1] + red[2] + red[3];
  float rn = rsqrtf(tot * (1.0f / 1024.0f) + 1.1920929e-7f);
  ushort4 p;
  p.x = f2b(v.x * rn); p.y = f2b(v.y * rn); p.z = f2b(v.z * rn); p.w = f2b(v.w * rn);
  *(ushort4*)(y + row * 1024 + tid * 4) = p;
}

// ---------------------------------------------------------------- rmsnorm (bf16 in, row = 1024)
__global__ __launch_bounds__(256) void rmsnorm_b16(const u16* __restrict__ x, u16* __restrict__ y) {
  const size_t row = blockIdx.x;
  const int tid = threadIdx.x;
  ushort4 h = ((const ushort4*)(x + row * 1024))[tid];
  float v0 = b2f(h.x), v1 = b2f(h.y), v2 = b2f(h.z), v3 = b2f(h.w);
  float ss = v0 * v0 + v1 * v1 + v2 * v2 + v3 * v3;
#pragma unroll
  for (int o = 32; o >= 1; o >>= 1) ss += __shfl_xor(ss, o);
  __shared__ float red[4];
  if ((tid & 63) == 0) red[tid >> 6] = ss;
  __syncthreads();
  float tot = red[0] + red[1] + red[2] + red[3];
  float rn = rsqrtf(tot * (1.0f / 1024.0f) + 1.1920929e-7f);
  ushort4 p;
  p.x = f2b(v0 * rn); p.y = f2b(v1 * rn); p.z = f2b(v2 * rn); p.w = f2b(v3 * rn);
  *(ushort4*)(y + row * 1024 + tid * 4) = p;
}

// ---------------------------------------------------------------- delta (3-phase, 64-chunks)
__global__ __launch_bounds__(256)
void delta_partial(const u16* __restrict__ y, const float* __restrict__ logits, float* __restrict__ Pp) {
  const int v = blockIdx.x * 256 + threadIdx.x;
  const int c = blockIdx.y, b = blockIdx.z;
  const float dec = sigmoidf_(logits[v]);
  const float ldc = logf(fmaxf(dec, 1e-6f));
  const float dc = expf(ldc);
  const u16* yp = y + ((size_t)b * 4096 + c * 64) * 1024 + v;
  float wv = expf((float)(4095 - (c * 64 + 63)) * ldc);
  float acc = 0.0f;
  for (int t = 63; t >= 0; --t) {
    acc += b2f(yp[(size_t)t * 1024]) * wv;
    wv *= dc;
  }
  Pp[((size_t)b * 64 + c) * 1024 + v] = acc;
}

__global__ __launch_bounds__(256) void delta_scan(float* __restrict__ Pp) {
  const int v = blockIdx.x * 256 + threadIdx.x;
  const int b = blockIdx.y;
  float run = 0.0f;
  for (int c = 0; c < 64; ++c) {
    size_t i = ((size_t)b * 64 + c) * 1024 + v;
    float t = Pp[i];
    Pp[i] = run;
    run += t;
  }
}

// writes x1 as bf16 ONLY
__global__ __launch_bounds__(256)
void delta_apply(const float* __restrict__ x0, const u16* __restrict__ y,
                 const float* __restrict__ logits, const float* __restrict__ scale_p,
                 const float* __restrict__ Pp, u16* __restrict__ x1b) {
  const int v = blockIdx.x * 256 + threadIdx.x;
  const int c = blockIdx.y, b = blockIdx.z;
  const float dec = sigmoidf_(logits[v]);
  const float ldc = logf(fmaxf(dec, 1e-6f));
  const float dc = expf(ldc);
  const float invd = expf(-ldc);
  const float sc = scale_p[0];
  float wv = expf((float)(4095 - c * 64) * ldc);
  float iw = expf(-(float)(4095 - c * 64) * ldc);
  float carry = Pp[((size_t)b * 64 + c) * 1024 + v];
  size_t base = ((size_t)b * 4096 + c * 64) * 1024 + v;
  for (int t = 0; t < 64; ++t) {
    size_t idx = base + (size_t)t * 1024;
    float o = x0[idx] + carry * fminf(iw, 1e8f) * sc;
    x1b[idx] = f2b(o);
    carry += b2f(y[idx]) * wv;
    wv *= invd;
    iw *= dc;
  }
}

// ---------------------------------------------------------------- GEMM variant S (m97 single-buffer)
// LDS exactly 32KB -> 5 blocks/CU via LDS bound; launch_bounds(256,4) keeps VGPR=64 (no spill).
// EPI 6: Cb = bf16(Xin + C*scale)        (fp32 residual in, bf16 out)
// EPI 8: Cb = bf16(b2f(Xb16) + C*scale)  (bf16 residual in, bf16 out; in-place safe)
template <int EPI>
__global__ __launch_bounds__(256, 4)
void pgemm_s(const u16* __restrict__ A, const u16* __restrict__ Bw,
             int M, int N, int K,
             u16* __restrict__ Cb,
             const float* __restrict__ Xin, float* __restrict__ Xout,
             const u16* __restrict__ Xb16,
             const float* __restrict__ bias, const float* __restrict__ scale_p) {
  __shared__ u16 sm[16384];  // 32 KB exactly: A[128][64] + B[128][64]; tl overlays
  const int tid = threadIdx.x;
  const int wid = tid >> 6, lane = tid & 63;
  const int gx = gridDim.x;
  const int id = blockIdx.y * gx + blockIdx.x;
  const int q8 = (gx * gridDim.y) >> 3;
  const int nid = (id & 7) * q8 + (id >> 3);
  const int bx = nid % gx, by = nid / gx;
  const int n0 = bx * 128, m0 = by * 128;
  const int wm = (wid >> 1) * 64, wn = (wid & 1) * 64;
  const int lr = lane & 15, lkc = lane >> 4;
  const int sw = lr & 7;
  const int c0 = (lkc ^ sw) * 8, c1 = ((lkc + 4) ^ sw) * 8;
  const int NT = K >> 6;
  const int srow = lane >> 3;
  const int scol = ((lane & 7) ^ srow) * 8;
  const u16* Ag = A + (size_t)(m0 + wid * 8 + srow) * K + scol;
  const u16* Bg = Bw + (size_t)(n0 + wid * 8 + srow) * K + scol;
  u16* const As = sm;
  u16* const Bs = sm + 8192;

  f32x4 acc[4][4] = {};

  for (int t = 0; t < NT; ++t) {
    {
      const u16* ga = Ag + (size_t)t * 64;
      const u16* gb = Bg + (size_t)t * 64;
      u16* la = As + wid * 512;
      u16* lb = Bs + wid * 512;
#pragma unroll
      for (int c = 0; c < 4; ++c) {
        g2l16(ga + (size_t)c * 32 * K, la + c * 2048);
        g2l16(gb + (size_t)c * 32 * K, lb + c * 2048);
      }
    }
    __syncthreads();
    s16x8 af[4][2], bfr[2][2][2];
#pragma unroll
    for (int i = 0; i < 4; ++i) {
      int base = (wm + i * 16 + lr) * 64;
      af[i][0] = *(const s16x8*)&As[base + c0];
      af[i][1] = *(const s16x8*)&As[base + c1];
    }
#pragma unroll
    for (int h = 0; h < 2; ++h)
#pragma unroll
      for (int j = 0; j < 2; ++j) {
        int base = (wn + h * 32 + j * 16 + lr) * 64;
        bfr[h][j][0] = *(const s16x8*)&Bs[base + c0];
        bfr[h][j][1] = *(const s16x8*)&Bs[base + c1];
      }
#pragma unroll
    for (int i = 0; i < 4; ++i)
#pragma unroll
      for (int h = 0; h < 2; ++h)
#pragma unroll
        for (int j = 0; j < 2; ++j) {
          acc[i][h * 2 + j] = mfma16(af[i][0], bfr[h][j][0], acc[i][h * 2 + j]);
          acc[i][h * 2 + j] = mfma16(af[i][1], bfr[h][j][1], acc[i][h * 2 + j]);
        }
    __syncthreads();
  }

  float* tl = (float*)(void*)sm + wid * 1088;
  const float sc = (EPI == 2 || EPI == 6 || EPI == 8) ? scale_p[0] : 0.0f;
  float4 bpf = {0.0f, 0.0f, 0.0f, 0.0f};
  if constexpr (EPI == 3 || EPI == 4) bpf = *(const float4*)&bias[n0 + wn + lr * 4];
#pragma unroll
  for (int i = 0; i < 4; ++i) {
#pragma unroll
    for (int j = 0; j < 4; ++j)
#pragma unroll
      for (int r = 0; r < 4; ++r)
        tl[(lkc * 4 + r) * 68 + j * 16 + lr] = acc[i][j][r];
#pragma unroll
    for (int p = 0; p < 4; ++p) {
      const int row = p * 4 + lkc, nl = lr * 4;
      f32x4 v = *(const f32x4*)&tl[row * 68 + nl];
      const int m = m0 + wm + i * 16 + row;
      const int n = n0 + wn + nl;
      const size_t idx = (size_t)m * N + n;
      if constexpr (EPI == 0) {
        ushort4 o = {f2b(v[0]), f2b(v[1]), f2b(v[2]), f2b(v[3])};
        *(ushort4*)&Cb[idx] = o;
      } else if constexpr (EPI == 2) {
        float4 x = *(const float4*)&Xin[idx];
        float4 o = {x.x + v[0] * sc, x.y + v[1] * sc, x.z + v[2] * sc, x.w + v[3] * sc};
        *(float4*)&Xout[idx] = o;
      } else if constexpr (EPI == 6) {
        float4 x = *(const float4*)&Xin[idx];
        ushort4 o = {f2b(x.x + v[0] * sc), f2b(x.y + v[1] * sc),
                     f2b(x.z + v[2] * sc), f2b(x.w + v[3] * sc)};
        *(ushort4*)&Cb[idx] = o;
      } else if constexpr (EPI == 8) {
        ushort4 hx = *(const ushort4*)&Xb16[idx];
        ushort4 o = {f2b(b2f(hx.x) + v[0] * sc), f2b(b2f(hx.y) + v[1] * sc),
                     f2b(b2f(hx.z) + v[2] * sc), f2b(b2f(hx.w) + v[3] * sc)};
        *(ushort4*)&Cb[idx] = o;
      } else if constexpr (EPI == 3) {
        float g0 = v[0] + bpf.x, g1 = v[1] + bpf.y, g2 = v[2] + bpf.z, g3 = v[3] + bpf.w;
        ushort4 o;
        o.x = f2b(g0 * sigmoidf_(1.59576912f * fmaf(0.044715f * g0, g0 * g0, g0)));
        o.y = f2b(g1 * sigmoidf_(1.59576912f * fmaf(0.044715f * g1, g1 * g1, g1)));
        o.z = f2b(g2 * sigmoidf_(1.59576912f * fmaf(0.044715f * g2, g2 * g2, g2)));
        o.w = f2b(g3 * sigmoidf_(1.59576912f * fmaf(0.044715f * g3, g3 * g3, g3)));
        *(ushort4*)&Cb[idx] = o;
      } else {
        float4 x = *(const float4*)&Xin[idx];
        float4 o = {x.x * sigmoidf_(v[0] + bpf.x), x.y * sigmoidf_(v[1] + bpf.y),
                    x.z * sigmoidf_(v[2] + bpf.z), x.w * sigmoidf_(v[3] + bpf.w)};
        *(float4*)&Xout[idx] = o;
      }
    }
  }
}

// ---------------------------------------------------------------- GEMM variant D (dbuf, full EPI set)
// EPI 7: gate = sigmoid(C+bias); Xb16 = bf16(b2f(P1)*gate); optional fp32 Xout
// EPI 8: Cb = bf16(b2f(P1) + C*scale)
// EPI 9: Xout = b2f(P1) + C*scale (fp32 out)
template <int EPI>
__global__ __launch_bounds__(256, 2)
void pgemm_d(const u16* __restrict__ A, const u16* __restrict__ Bw,
             int M, int N, int K,
             u16* __restrict__ Cb,
             const float* __restrict__ Xin, float* __restrict__ Xout,
             u16* __restrict__ Xb16,
             const float* __restrict__ bias, const float* __restrict__ scale_p,
             u16* __restrict__ P1, u16* __restrict__ P2, u16* __restrict__ P3) {
  __shared__ u16 sm[32768];
  const int tid = threadIdx.x;
  const int wid = tid >> 6, lane = tid & 63;
  const int gx = gridDim.x;
  const int id = blockIdx.y * gx + blockIdx.x;
  const int q8 = (gx * gridDim.y) >> 3;
  const int nid = (id & 7) * q8 + (id >> 3);
  const int bx = nid % gx, by = nid / gx;
  const int n0 = bx * 128, m0 = by * 128;
  const int wm = (wid >> 1) * 64, wn = (wid & 1) * 64;
  const int lr = lane & 15, lkc = lane >> 4;
  const int sw = lr & 7;
  const int c0 = (lkc ^ sw) * 8, c1 = ((lkc + 4) ^ sw) * 8;
  const int NT = K >> 6;
  const int srow = lane >> 3;
  const int scol = ((lane & 7) ^ srow) * 8;
  const u16* Ag = A + (size_t)(m0 + wid * 8 + srow) * K + scol;
  const u16* Bg = Bw + (size_t)(n0 + wid * 8 + srow) * K + scol;
  u16* const AL0 = sm;          u16* const BL0 = sm + 8192;
  u16* const AL1 = sm + 16384;  u16* const BL1 = sm + 24576;

  f32x4 acc[4][4] = {};

  auto STA = [&](int tau) {
    const u16* g = Ag + (size_t)tau * 64;
    u16* l = ((tau & 1) ? AL1 : AL0) + wid * 512;
#pragma unroll
    for (int c = 0; c < 4; ++c) g2l16(g + (size_t)c * 32 * K, l + c * 2048);
  };
  auto STB = [&](int tau) {
    const u16* g = Bg + (size_t)tau * 64;
    u16* l = ((tau & 1) ? BL1 : BL0) + wid * 512;
#pragma unroll
    for (int c = 0; c < 4; ++c) g2l16(g + (size_t)c * 32 * K, l + c * 2048);
  };
  auto RDA = [&](int tau, s16x8 (&d)[4][2]) {
    const u16* Ab = (tau & 1) ? AL1 : AL0;
#pragma unroll
    for (int i = 0; i < 4; ++i) {
      int base = (wm + i * 16 + lr) * 64;
      d[i][0] = *(const s16x8*)&Ab[base + c0];
      d[i][1] = *(const s16x8*)&Ab[base + c1];
    }
  };
  auto RDB = [&](int tau, int h, s16x8 (&d)[2][2]) {
    const u16* Bb = (tau & 1) ? BL1 : BL0;
#pragma unroll
    for (int j = 0; j < 2; ++j) {
      int base = (wn + h * 32 + j * 16 + lr) * 64;
      d[j][0] = *(const s16x8*)&Bb[base + c0];
      d[j][1] = *(const s16x8*)&Bb[base + c1];
    }
  };
  auto MM = [&](s16x8 (&Ar)[4][2], s16x8 (&Br)[2][2], int jo) {
    __builtin_amdgcn_s_setprio(1);
#pragma unroll
    for (int i = 0; i < 4; ++i)
#pragma unroll
      for (int j = 0; j < 2; ++j) {
        acc[i][jo + j] = mfma16(Ar[i][0], Br[j][0], acc[i][jo + j]);
        acc[i][jo + j] = mfma16(Ar[i][1], Br[j][1], acc[i][jo + j]);
      }
    __builtin_amdgcn_s_setprio(0);
  };

  s16x8 Ae[4][2], Ao[4][2], B0r[2][2], B1r[2][2];
  STA(0); STB(0);
  if (NT > 1) { STA(1); STB(1); }
  WAITV8(); BAR();
  RDA(0, Ae); RDB(0, 0, B0r);

  for (int t = 0; t < NT; t += 2) {
    RDB(t, 1, B1r);
    if (t + 2 < NT) STA(t + 2);
    BAR(); WAITL0();
    MM(Ae, B0r, 0);
    BAR();
    if (t + 2 < NT) { STB(t + 2); WAITV8(); } else { WAITV0(); }
    BAR();
    if (t + 1 < NT) { RDA(t + 1, Ao); RDB(t + 1, 0, B0r); }
    WAITL0();
    MM(Ae, B1r, 2);
    BAR();
    if (t + 1 >= NT) break;
    RDB(t + 1, 1, B1r);
    if (t + 3 < NT) STA(t + 3);
    BAR(); WAITL0();
    MM(Ao, B0r, 0);
    BAR();
    if (t + 3 < NT) { STB(t + 3); WAITV8(); } else { WAITV0(); }
    BAR();
    if (t + 2 < NT) { RDA(t + 2, Ae); RDB(t + 2, 0, B0r); }
    WAITL0();
    MM(Ao, B1r, 2);
    BAR();
  }

  float* tl = (float*)(void*)sm + wid * 1088;

  if constexpr (EPI == 5) {
    if (bx < 4) {
      u16* dst = (bx < 2) ? Cb : P1;
      const int nb = (bx & 1) * 128;
#pragma unroll
      for (int i = 0; i < 4; ++i) {
#pragma unroll
        for (int j = 0; j < 4; ++j)
#pragma unroll
          for (int r = 0; r < 4; ++r)
            tl[(lkc * 4 + r) * 68 + j * 16 + lr] = acc[i][j][r];
#pragma unroll
        for (int p = 0; p < 4; ++p) {
          const int row = p * 4 + lkc, nl = lr * 4;
          f32x4 v = *(const f32x4*)&tl[row * 68 + nl];
          const int m = m0 + wm + i * 16 + row;
          ushort4 o = {f2b(v[0]), f2b(v[1]), f2b(v[2]), f2b(v[3])};
          *(ushort4*)&dst[(size_t)m * 256 + nb + wn + nl] = o;
        }
      }
      if (bx >= 2) {
        const float ld5 = logf(sigmoidf_(scale_p[0]));
        u16* CT = sm;
        __syncthreads();
#pragma unroll
        for (int i = 0; i < 4; ++i)
#pragma unroll
          for (int j = 0; j < 4; ++j)
#pragma unroll
            for (int r = 0; r < 4; ++r) {
              int ml = wm + i * 16 + lkc * 4 + r;
              int nl = wn + j * 16 + lr;
              float g = expf(ld5 * (float)(ml & 63));
              CT[nl * 136 + ml] = f2b(acc[i][j][r] * g);
            }
        __syncthreads();
        int d = tid >> 1, off = (tid & 1) * 64;
        size_t base = ((size_t)(m0 >> 12) * 256 + (bx - 2) * 128 + d) * 4096 + (m0 & 4095) + off;
#pragma unroll
        for (int p = 0; p < 8; ++p)
          *(uint4*)&P3[base + p * 8] = *(const uint4*)&CT[d * 136 + off + p * 8];
      }
    } else {
      u16* CT = sm;
      __syncthreads();
#pragma unroll
      for (int i = 0; i < 4; ++i)
#pragma unroll
        for (int j = 0; j < 4; ++j)
#pragma unroll
          for (int r = 0; r < 4; ++r) {
            int ml = wm + i * 16 + lkc * 4 + r;
            int nl = wn + j * 16 + lr;
            CT[nl * 136 + ml] = f2b(acc[i][j][r]);
          }
      __syncthreads();
      int d = tid >> 1, off = (tid & 1) * 64;
      size_t base = ((size_t)(m0 >> 12) * 256 + (bx - 4) * 128 + d) * 4096 + (m0 & 4095) + off;
#pragma unroll
      for (int p = 0; p < 8; ++p)
        *(uint4*)&P2[base + p * 8] = *(const uint4*)&CT[d * 136 + off + p * 8];
    }
  } else {
    const float sc = (EPI == 2 || EPI == 6 || EPI == 8 || EPI == 9) ? scale_p[0] : 0.0f;
    float4 bpf = {0.0f, 0.0f, 0.0f, 0.0f};
    if constexpr (EPI == 3 || EPI == 4 || EPI == 7) bpf = *(const float4*)&bias[n0 + wn + lr * 4];
#pragma unroll
    for (int i = 0; i < 4; ++i) {
#pragma unroll
      for (int j = 0; j < 4; ++j)
#pragma unroll
        for (int r = 0; r < 4; ++r)
          tl[(lkc * 4 + r) * 68 + j * 16 + lr] = acc[i][j][r];
#pragma unroll
      for (int p = 0; p < 4; ++p) {
        const int row = p * 4 + lkc, nl = lr * 4;
        f32x4 v = *(const f32x4*)&tl[row * 68 + nl];
        const int m = m0 + wm + i * 16 + row;
        const int n = n0 + wn + nl;
        const size_t idx = (size_t)m * N + n;
        if constexpr (EPI == 0) {
          ushort4 o = {f2b(v[0]), f2b(v[1]), f2b(v[2]), f2b(v[3])};
          *(ushort4*)&Cb[idx] = o;
        } else if constexpr (EPI == 2) {
          float4 x = *(const float4*)&Xin[idx];
          float4 o = {x.x + v[0] * sc, x.y + v[1] * sc, x.z + v[2] * sc, x.w + v[3] * sc};
          *(float4*)&Xout[idx] = o;
          if (Xb16) {
            ushort4 ob = {f2b(o.x), f2b(o.y), f2b(o.z), f2b(o.w)};
            *(ushort4*)&Xb16[idx] = ob;
          }
        } else if constexpr (EPI == 6) {
          float4 x = *(const float4*)&Xin[idx];
          ushort4 o = {f2b(x.x + v[0] * sc), f2b(x.y + v[1] * sc),
                       f2b(x.z + v[2] * sc), f2b(x.w + v[3] * sc)};
          *(ushort4*)&Cb[idx] = o;
        } else if constexpr (EPI == 8) {
          ushort4 hx = *(const ushort4*)&P1[idx];
          ushort4 o = {f2b(b2f(hx.x) + v[0] * sc), f2b(b2f(hx.y) + v[1] * sc),
                       f2b(b2f(hx.z) + v[2] * sc), f2b(b2f(hx.w) + v[3] * sc)};
          *(ushort4*)&Cb[idx] = o;
        } else if constexpr (EPI == 9) {
          ushort4 hx = *(const ushort4*)&P1[idx];
          float4 o = {b2f(hx.x) + v[0] * sc, b2f(hx.y) + v[1] * sc,
                      b2f(hx.z) + v[2] * sc, b2f(hx.w) + v[3] * sc};
          *(float4*)&Xout[idx] = o;
        } else if constexpr (EPI == 3) {
          float g0 = v[0] + bpf.x, g1 = v[1] + bpf.y, g2 = v[2] + bpf.z, g3 = v[3] + bpf.w;
          ushort4 o;
          o.x = f2b(g0 * sigmoidf_(1.59576912f * fmaf(0.044715f * g0, g0 * g0, g0)));
          o.y = f2b(g1 * sigmoidf_(1.59576912f * fmaf(0.044715f * g1, g1 * g1, g1)));
          o.z = f2b(g2 * sigmoidf_(1.59576912f * fmaf(0.044715f * g2, g2 * g2, g2)));
          o.w = f2b(g3 * sigmoidf_(1.59576912f * fmaf(0.044715f * g3, g3 * g3, g3)));
          *(ushort4*)&Cb[idx] = o;
        } else if constexpr (EPI == 4) {
          float4 x = *(const float4*)&Xin[idx];
          float4 o = {x.x * sigmoidf_(v[0] + bpf.x), x.y * sigmoidf_(v[1] + bpf.y),
                      x.z * sigmoidf_(v[2] + bpf.z), x.w * sigmoidf_(v[3] + bpf.w)};
          *(float4*)&Xout[idx] = o;
          if (Xb16) {
            ushort4 ob = {f2b(o.x), f2b(o.y), f2b(o.z), f2b(o.w)};
            *(ushort4*)&Xb16[idx] = ob;
          }
        } else {  // EPI 7
          ushort4 hx = *(const ushort4*)&P1[idx];
          float4 o = {b2f(hx.x) * sigmoidf_(v[0] + bpf.x), b2f(hx.y) * sigmoidf_(v[1] + bpf.y),
                      b2f(hx.z) * sigmoidf_(v[2] + bpf.z), b2f(hx.w) * sigmoidf_(v[3] + bpf.w)};
          if (Xout) *(float4*)&Xout[idx] = o;
          ushort4 ob = {f2b(o.x), f2b(o.y), f2b(o.z), f2b(o.w)};
          *(ushort4*)&Xb16[idx] = ob;
        }
      }
    }
  }
}

// ---------------------------------------------------------------- chunked linear attention (bf16 G)
__global__ __launch_bounds__(256, 2)
void chunk_G(const u16* __restrict__ vT, const u16* __restrict__ kTs, u16* __restrict__ Gp) {
  __shared__ u16 sm2[16384];
  const int c = blockIdx.x, eh = blockIdx.y >> 1, dh = blockIdx.y & 1, b = blockIdx.z;
  const int tid = threadIdx.x, wid = tid >> 6, lane = tid & 63;
  u16* AL = sm2; u16* BL = sm2 + 8192;
  const u16* As = vT + (size_t)(b * 256 + eh * 128) * 4096 + c * 64;
  const u16* Bs = kTs + (size_t)(b * 256 + dh * 128) * 4096 + c * 64;
  const int r8 = lane >> 3, sc8 = ((lane & 7) ^ (lane >> 3)) * 8;
#pragma unroll
  for (int p = 0; p < 4; ++p) {
    int ch = p * 4 + wid;
    int row = ch * 8 + r8;
    g2l16(As + (size_t)row * 4096 + sc8, AL + ch * 512);
    g2l16(Bs + (size_t)row * 4096 + sc8, BL + ch * 512);
  }
  __syncthreads();
  const int wm = (wid >> 1) * 64, wn = (wid & 1) * 64;
  const int lr = lane & 15, lkc = lane >> 4, sw = lr & 7;
  const int c0 = (lkc ^ sw) * 8, c1 = ((lkc + 4) ^ sw) * 8;
  s16x8 af[4][2], bf[4][2];
#pragma unroll
  for (int i = 0; i < 4; ++i) {
    int ba = (wm + i * 16 + lr) * 64;
    af[i][0] = *(const s16x8*)&AL[ba + c0];
    af[i][1] = *(const s16x8*)&AL[ba + c1];
    int bb = (wn + i * 16 + lr) * 64;
    bf[i][0] = *(const s16x8*)&BL[bb + c0];
    bf[i][1] = *(const s16x8*)&BL[bb + c1];
  }
  f32x4 acc[4][4] = {};
#pragma unroll
  for (int i = 0; i < 4; ++i)
#pragma unroll
    for (int j = 0; j < 4; ++j) {
      acc[i][j] = mfma16(af[i][0], bf[j][0], acc[i][j]);
      acc[i][j] = mfma16(af[i][1], bf[j][1], acc[i][j]);
    }
  u16* Gb = Gp + (size_t)(b * 64 + c) * 65536;
#pragma unroll
  for (int i = 0; i < 4; ++i)
#pragma unroll
    for (int j = 0; j < 4; ++j)
#pragma unroll
      for (int r = 0; r < 4; ++r) {
        int e = eh * 128 + wm + i * 16 + lkc * 4 + r;
        int d = dh * 128 + wn + j * 16 + lr;
        Gb[(size_t)e * 256 + d] = f2b(acc[i][j][r]);
      }
}

// M_c = G'_{c+1} + gamma^64 * M_{c+1}; M_63 = 0.  4-deep load pipeline.
__global__ __launch_bounds__(256)
void scan_M(const u16* __restrict__ Gp, u16* __restrict__ Mb, const float* __restrict__ dlogit) {
  const int b = blockIdx.y;
  const size_t idx = (size_t)blockIdx.x * 256 + threadIdx.x;
  const float ld = logf(sigmoidf_(dlogit[0]));
  const float g64 = expf(64.0f * ld);
  const u16* G = Gp + (size_t)b * 64 * 65536 + idx;
  u16* M = Mb + (size_t)b * 64 * 65536 + idx;
  const size_t S = 65536;
  float m = 0.0f;
  M[(size_t)63 * S] = 0;
  int c = 62;
  for (; c >= 3; c -= 4) {
    u16 h0 = G[(size_t)(c + 1) * S];
    u16 h1 = G[(size_t)c * S];
    u16 h2 = G[(size_t)(c - 1) * S];
    u16 h3 = G[(size_t)(c - 2) * S];
    m = b2f(h0) + g64 * m; M[(size_t)c * S] = f2b(m);
    m = b2f(h1) + g64 * m; M[(size_t)(c - 1) * S] = f2b(m);
    m = b2f(h2) + g64 * m; M[(size_t)(c - 2) * S] = f2b(m);
    m = b2f(h3) + g64 * m; M[(size_t)(c - 3) * S] = f2b(m);
  }
  for (; c >= 0; --c) {
    m = b2f(G[(size_t)(c + 1) * S]) + g64 * m;
    M[(size_t)c * S] = f2b(m);
  }
}

__global__ __launch_bounds__(256, 2)
void chunk_R(const u16* __restrict__ q, const u16* __restrict__ k,
             const u16* __restrict__ vT, const u16* __restrict__ Mb,
             u16* __restrict__ R, const float* __restrict__ dlogit) {
  __shared__ u16 qL[16384];
  __shared__ u16 shA[16384];
  const int c = blockIdx.x, eh = blockIdx.y, b = blockIdx.z;
  const int tid = threadIdx.x, wid = tid >> 6, lane = tid & 63;
  const float ld = logf(sigmoidf_(dlogit[0]));
  const int r8 = lane >> 3, sc8 = ((lane & 7) ^ (lane >> 3)) * 8;
  const int lr = lane & 15, lkc = lane >> 4, g4 = lkc * 4;
  const int sw = lr & 7;
  const int c0 = (lkc ^ sw) * 8, c1 = ((lkc + 4) ^ sw) * 8;

  const u16* qsrc = q + ((size_t)b * 4096 + c * 64) * 256;
  const u16* ksrc = k + ((size_t)b * 4096 + c * 64) * 256;
  const u16* msrc = Mb + ((size_t)(b * 64 + c) * 256 + eh * 128) * 256;
  const u16* vsrc = vT + (size_t)(b * 256 + eh * 128) * 4096 + c * 64;

#pragma unroll
  for (int kt = 0; kt < 4; ++kt)
#pragma unroll
    for (int p = 0; p < 2; ++p) {
      int ch = p * 4 + wid;
      int row = ch * 8 + r8;
      g2l16(qsrc + (size_t)row * 256 + kt * 64 + sc8, qL + kt * 4096 + ch * 512);
    }
#pragma unroll
  for (int p = 0; p < 4; ++p) {
    int ch = p * 4 + wid;
    int row = ch * 8 + r8;
    g2l16(msrc + (size_t)row * 256 + sc8, shA + ch * 512);
  }
  f32x4 accx[4][2] = {};
  for (int dt = 0; dt < 4; ++dt) {
    if (dt < 3) {
      u16* dst = shA + ((dt + 1) & 1) * 8192;
#pragma unroll
      for (int p = 0; p < 4; ++p) {
        int ch = p * 4 + wid;
        int row = ch * 8 + r8;
        g2l16(msrc + (size_t)row * 256 + (dt + 1) * 64 + sc8, dst + ch * 512);
      }
      WAITV4();
    } else {
      WAITV0();
    }
    BAR();
    const u16* mt = shA + (dt & 1) * 8192;
    const u16* qt = qL + dt * 4096;
    s16x8 aq[4][2], bm[2][2];
#pragma unroll
    for (int i = 0; i < 4; ++i) {
      int ba = (i * 16 + lr) * 64;
      aq[i][0] = *(const s16x8*)&qt[ba + c0];
      aq[i][1] = *(const s16x8*)&qt[ba + c1];
    }
#pragma unroll
    for (int j = 0; j < 2; ++j) {
      int ba = (wid * 32 + j * 16 + lr) * 64;
      bm[j][0] = *(const s16x8*)&mt[ba + c0];
      bm[j][1] = *(const s16x8*)&mt[ba + c1];
    }
#pragma unroll
    for (int i = 0; i < 4; ++i)
#pragma unroll
      for (int j = 0; j < 2; ++j) {
        accx[i][j] = mfma16(aq[i][0], bm[j][0], accx[i][j]);
        accx[i][j] = mfma16(aq[i][1], bm[j][1], accx[i][j]);
      }
    BAR();
  }
#pragma unroll
  for (int kt = 0; kt < 4; ++kt)
#pragma unroll
    for (int p = 0; p < 2; ++p) {
      int ch = p * 4 + wid;
      int row = ch * 8 + r8;
      g2l16(ksrc + (size_t)row * 256 + kt * 64 + sc8, shA + kt * 4096 + ch * 512);
    }
  __syncthreads();
  f32x4 accs[4] = {};
#pragma unroll
  for (int kt = 0; kt < 4; ++kt) {
    const u16* qt = qL + kt * 4096;
    const u16* klt = shA + kt * 4096;
    s16x8 aq[4][2], bk[2];
#pragma unroll
    for (int i = 0; i < 4; ++i) {
      int ba = (i * 16 + lr) * 64;
      aq[i][0] = *(const s16x8*)&qt[ba + c0];
      aq[i][1] = *(const s16x8*)&qt[ba + c1];
    }
    {
      int ba = (wid * 16 + lr) * 64;
      bk[0] = *(const s16x8*)&klt[ba + c0];
      bk[1] = *(const s16x8*)&klt[ba + c1];
    }
#pragma unroll
    for (int i = 0; i < 4; ++i) {
      accs[i] = mfma16(aq[i][0], bk[0], accs[i]);
      accs[i] = mfma16(aq[i][1], bk[1], accs[i]);
    }
  }
  __syncthreads();
  u16* PL = shA;
  u16* vTL = shA + 4608;
#pragma unroll
  for (int p = 0; p < 4; ++p) {
    int ch = p * 4 + wid;
    int row = ch * 8 + r8;
    g2l16(vsrc + (size_t)row * 4096 + sc8, vTL + ch * 512);
  }
#pragma unroll
  for (int i = 0; i < 4; ++i)
#pragma unroll
    for (int r = 0; r < 4; ++r) {
      int gi = i * 16 + g4 + r;
      int gj = wid * 16 + lr;
      float pw = (gj > gi) ? expf(ld * (float)(gj - gi - 1)) : 0.0f;
      PL[gi * 72 + gj] = f2b(accs[i][r] * pw);
    }
  __syncthreads();
  f32x4 acci[4][2] = {};
  {
    s16x8 pa[4][2], bv[2][2];
#pragma unroll
    for (int i = 0; i < 4; ++i) {
      pa[i][0] = *(const s16x8*)&PL[(i * 16 + lr) * 72 + lkc * 8];
      pa[i][1] = *(const s16x8*)&PL[(i * 16 + lr) * 72 + 32 + lkc * 8];
    }
#pragma unroll
    for (int j = 0; j < 2; ++j) {
      int ba = (wid * 32 + j * 16 + lr) * 64;
      bv[j][0] = *(const s16x8*)&vTL[ba + c0];
      bv[j][1] = *(const s16x8*)&vTL[ba + c1];
    }
#pragma unroll
    for (int i = 0; i < 4; ++i)
#pragma unroll
      for (int j = 0; j < 2; ++j) {
        acci[i][j] = mfma16(pa[i][0], bv[j][0], acci[i][j]);
        acci[i][j] = mfma16(pa[i][1], bv[j][1], acci[i][j]);
      }
  }
  u16* Ro = R + ((size_t)b * 4096 + c * 64) * 256 + eh * 128;
#pragma unroll
  for (int i = 0; i < 4; ++i)
#pragma unroll
    for (int r = 0; r < 4; ++r) {
      int gi = i * 16 + g4 + r;
      float xf = expf(ld * (float)(63 - gi));
#pragma unroll
      for (int j = 0; j < 2; ++j) {
        int ge = wid * 32 + j * 16 + lr;
        Ro[(size_t)gi * 256 + ge] = f2b(acci[i][j][r] + xf * accx[i][j][r]);
      }
    }
}

// ---------------------------------------------------------------- host
extern "C" void kernel_launch(void* const* d_in, const int* in_sizes, int n_in,
                              void* d_out, int out_size, void* d_ws, size_t ws_size,
                              hipStream_t stream) {
  const float* x0 = (const float*)d_in[0];
  const float* Wq = (const float*)d_in[1];
  const float* Wk = (const float*)d_in[2];
  const float* Wv = (const float*)d_in[3];
  const float* Wo = (const float*)d_in[4];
  const float* dlog = (const float*)d_in[5];
  const float* dscale = (const float*)d_in[6];
  const float* th_dec = (const float*)d_in[7];
  const float* th_sc = (const float*)d_in[8];
  const float* ga_dec = (const float*)d_in[9];
  const float* ga_sc = (const float*)d_in[10];
  const float* adw = (const float*)d_in[11];
  const float* auw = (const float*)d_in[12];
  const float* a_upb = (const float*)d_in[13];
  const float* bdw = (const float*)d_in[14];
  const float* buw = (const float*)d_in[15];
  const float* bbias = (const float*)d_in[16];
  const float* bscale = (const float*)d_in[17];

  char* w = (char*)d_ws;
  float* xA = (float*)w;                       // 33,554,432 (kT scratch stages 2/5)
  u16* y = (u16*)(w + 33554432);               // 16,777,216 -> M buffer during attn
  u16* xb = (u16*)(w + 50331648);              // 16,777,216 (bf16 residual chain x1..x4)
  u16* qb = (u16*)(w + 67108864);              // 4,194,304
  u16* kb = (u16*)(w + 71303168);              // 4,194,304
  u16* vT = (u16*)(w + 75497472);              // 4,194,304
  u16* Rb = (u16*)(w + 79691776);              // 4,194,304
  u16* gb = (u16*)(w + 83886080);              // 2,097,152  (also Pp during stage 1)
  u16* hb = (u16*)(w + 85983232);              // 33,554,432 -> G (bf16) during attn
  u16* Gp = hb;
  u16* Mbuf = y;
  u16* kTs2 = (u16*)xA;
  u16* kTs5 = (u16*)xA;
  float* Pp = (float*)gb;
  u16* Wqkvb = (u16*)(w + 119799808);          // 1,572,864
  u16* Wob = (u16*)(w + 121372672);            // 524,288
  u16* adb = (u16*)(w + 121896960);            // 262,144
  u16* aub = (u16*)(w + 122159104);            // 262,144
  u16* bdb = (u16*)(w + 122421248);            // 4,194,304
  u16* bub = (u16*)(w + 126615552);            // 4,194,304
  float* xB = (float*)d_out;

  cast_all<<<5376, 256, 0, stream>>>(Wq, Wk, Wv, Wo, adw, auw, bdw, buw,
                                     Wqkvb, Wob, adb, aub, bdb, bub);

  // ---- stage 1: x1 = x0 + delta(rmsnorm(x0))   (bf16 only -> xb)
  rmsnorm_k<<<8192, 256, 0, stream>>>(x0, y);
  delta_partial<<<dim3(4, 64, 2), 256, 0, stream>>>(y, dlog, Pp);
  delta_scan<<<dim3(4, 2), 256, 0, stream>>>(Pp);
  delta_apply<<<dim3(4, 64, 2), 256, 0, stream>>>(x0, y, dlog, dscale, Pp, xb);

  // ---- stage 2: x2 = x1 + memory(rmsnorm(x1), theta)   (EPI8: bf16 in-place on xb)
  rmsnorm_b16<<<8192, 256, 0, stream>>>(xb, y);
  pgemm_d<5><<<dim3(6, 64), 256, 0, stream>>>(y, Wqkvb, 8192, 768, 1024, qb, nullptr, nullptr, nullptr, nullptr, th_dec, kb, vT, kTs2);
  chunk_G<<<dim3(64, 4, 2), 256, 0, stream>>>(vT, kTs2, Gp);
  scan_M<<<dim3(256, 2), 256, 0, stream>>>(Gp, Mbuf, th_dec);
  chunk_R<<<dim3(64, 2, 2), 256, 0, stream>>>(qb, kb, vT, Mbuf, Rb, th_dec);
  pgemm_d<8><<<dim3(8, 64), 256, 0, stream>>>(Rb, Wob, 8192, 1024, 256, xb, nullptr, nullptr, nullptr, nullptr, th_sc, xb, nullptr, nullptr);

  // ---- stage 3: x3 = alpha(x2)   (bf16 only -> xb)
  pgemm_d<0><<<dim3(1, 64), 256, 0, stream>>>(xb, adb, 8192, 128, 1024, gb, nullptr, nullptr, nullptr, nullptr, nullptr, nullptr, nullptr, nullptr);
  pgemm_d<7><<<dim3(8, 64), 256, 0, stream>>>(gb, aub, 8192, 1024, 128, nullptr, nullptr, nullptr, xb, a_upb, nullptr, xb, nullptr, nullptr);

  // ---- stage 4: x4 = x3 + beta(rmsnorm(x3))   (EPI8: bf16 residual from xb, in-place)
  rmsnorm_b16<<<8192, 256, 0, stream>>>(xb, y);
  pgemm_s<3><<<dim3(16, 64), 256, 0, stream>>>(y, bdb, 8192, 2048, 1024, hb, nullptr, nullptr, nullptr, bbias, nullptr);
  pgemm_s<8><<<dim3(8, 64), 256, 0, stream>>>(hb, bub, 8192, 1024, 2048, xb, nullptr, nullptr, xb, nullptr, bscale);

  // ---- stage 5: out = x4 + memory(rmsnorm(x4), gamma)   (kT -> xA scratch; xb preserved)
  rmsnorm_b16<<<8192, 256, 0, stream>>>(xb, y);
  pgemm_d<5><<<dim3(6, 64), 256, 0, stream>>>(y, Wqkvb, 8192, 768, 1024, qb, nullptr, nullptr, nullptr, nullptr, ga_dec, kb, vT, kTs5);
  chunk_G<<<dim3(64, 4, 2), 256, 0, stream>>>(vT, kTs5, Gp);
  scan_M<<<dim3(256, 2), 256, 0, stream>>>(Gp, Mbuf, ga_dec);
  chunk_R<<<dim3(64, 2, 2), 256, 0, stream>>>(qb, kb, vT, Mbuf, Rb, ga_dec);
  pgemm_d<9><<<dim3(8, 64), 256, 0, stream>>>(Rb, Wob, 8192, 1024, 256, nullptr, nullptr, xB, nullptr, nullptr, ga_sc, xb, nullptr, nullptr);
}